// Round 4
// baseline (766.841 us; speedup 1.0000x reference)
//
#include <hip/hip_runtime.h>
#include <hip/hip_bf16.h>

#define N_E 10000
#define N_KC 2000
#define ALPHA 0.2f
#define NEG_INF (-9.0e15f)
#define TR 16

// ---- static device scratch (no d_ws dependence; fully rewritten every call)
__device__ float g_kcWh[N_KC * 256];   // 2 MB
__device__ float g_rdwT[512 * 256];    // 512 KB
__device__ float g_t[N_KC];
__device__ float g_s[N_E];
__device__ float g_w1a1[256];

// ---- runtime input-dtype probe: true if float tensors are f32, false if bf16.
__device__ __forceinline__ bool detect_f32(const void* w1) {
  const unsigned short* p = (const unsigned short*)w1;
  int outliers = 0;
  for (int i = 0; i < 512; i += 2) {
    unsigned short u = p[i];
    int e = (u >> 7) & 0xFF;
    if (u != 0 && (e < 97 || e > 135)) outliers++;
  }
  return outliers > 32;
}

// Branch-safe dual-dtype load: offset selected BEFORE one in-bounds dword load.
__device__ __forceinline__ float ldin(const void* p, size_t i, bool f32) {
  size_t off = f32 ? (i << 2) : ((i << 1) & ~(size_t)3);
  unsigned int w = *(const unsigned int*)((const char*)p + off);
  if (f32) return __uint_as_float(w);
  unsigned int hv = (i & 1) ? (w & 0xFFFF0000u) : (w << 16);
  return __uint_as_float(hv);
}

// ---- kernel 1: rdwT[f][c] = rd_w[c][f]; w1a1[k] = sum_o W1[k,o]*a1[o]
__global__ __launch_bounds__(256) void prep_kernel(
    const void* __restrict__ W1, const void* __restrict__ a,
    const void* __restrict__ rd_w) {
  bool f32 = detect_f32(W1);
  int tid = threadIdx.x;
  int b = blockIdx.x;
  if (b < 512) {
    g_rdwT[b * 256 + tid] = ldin(rd_w, (size_t)tid * 512 + b, f32);
  } else {
    float acc = 0.f;
    for (int o = 0; o < 256; ++o)
      acc = fmaf(ldin(W1, (size_t)tid * 256 + o, f32), ldin(a, o, f32), acc);
    g_w1a1[tid] = acc;
  }
}

// ---- kernel 2: kcWh[j][o] = sum_k kc_h[j,k]*W1[k,o];  t[j] = kcWh[j]·a2 ----
__global__ __launch_bounds__(256) void kc_kernel(
    const void* __restrict__ kc_h, const void* __restrict__ W1,
    const void* __restrict__ a) {
  bool f32 = detect_f32(W1);
  __shared__ float kcs[256];
  __shared__ float red[4];
  int tid = threadIdx.x;
  int j = blockIdx.x;
  kcs[tid] = ldin(kc_h, (size_t)j * 256 + tid, f32);
  __syncthreads();
  float acc = 0.f;
  for (int k = 0; k < 256; k += 4) {
    float4 kv = *(const float4*)&kcs[k];
    acc = fmaf(kv.x, ldin(W1, (size_t)(k + 0) * 256 + tid, f32), acc);
    acc = fmaf(kv.y, ldin(W1, (size_t)(k + 1) * 256 + tid, f32), acc);
    acc = fmaf(kv.z, ldin(W1, (size_t)(k + 2) * 256 + tid, f32), acc);
    acc = fmaf(kv.w, ldin(W1, (size_t)(k + 3) * 256 + tid, f32), acc);
  }
  g_kcWh[j * 256 + tid] = acc;
  float v = acc * ldin(a, 256 + tid, f32);
  for (int off = 32; off; off >>= 1) v += __shfl_down(v, off, 64);
  if ((tid & 63) == 0) red[tid >> 6] = v;
  __syncthreads();
  if (tid == 0) g_t[j] = red[0] + red[1] + red[2] + red[3];
}

// ---- kernel 3: s[i] = exercise_h[i]·w1a1 (one wave per row) ----
__global__ __launch_bounds__(256) void s_kernel(
    const void* __restrict__ exh, const void* __restrict__ W1) {
  bool f32 = detect_f32(W1);
  int tid = threadIdx.x;
  int lane = tid & 63, w = tid >> 6;
  int i = blockIdx.x * 4 + w;
  float acc = 0.f;
  for (int k = lane; k < 256; k += 64)
    acc = fmaf(ldin(exh, (size_t)i * 256 + k, f32), g_w1a1[k], acc);
  for (int off = 32; off; off >>= 1) acc += __shfl_down(acc, off, 64);
  if (lane == 0) g_s[i] = acc;
}

// ---- kernel 4: fused attention + aggregation + ex_Eh + output GEMM + ELU ----
__global__ __launch_bounds__(256) void main_kernel(
    const void* __restrict__ exh, const int* __restrict__ adj,
    const void* __restrict__ E, const void* __restrict__ W1,
    const void* __restrict__ rd_b, float* __restrict__ out) {
  bool f32 = detect_f32(W1);
  __shared__ float t_s[N_KC];
  __shared__ float buf[TR * 512];
  __shared__ float s_sh[TR], maxv[TR], denom[TR];
  __shared__ float red[TR][4];

  int tid = threadIdx.x;
  int i0 = blockIdx.x * TR;

  for (int j = tid; j < N_KC; j += 256) t_s[j] = g_t[j];
  if (tid < TR) s_sh[tid] = g_s[i0 + tid];
  __syncthreads();

  // ---- pass 1: per-row masked max of logits ----
  for (int r = 0; r < TR; ++r) {
    const int* arow = adj + (size_t)(i0 + r) * N_KC;
    float sv = s_sh[r];
    float m = NEG_INF;
    for (int j = tid; j < N_KC; j += 256) {
      if (arow[j] > 0) {
        float x = sv + t_s[j];
        float lx = x > 0.f ? x : ALPHA * x;
        m = fmaxf(m, lx);
      }
    }
    for (int off = 32; off; off >>= 1) m = fmaxf(m, __shfl_down(m, off, 64));
    if ((tid & 63) == 0) red[r][tid >> 6] = m;
  }
  __syncthreads();
  if (tid < TR) {
    float mm = fmaxf(fmaxf(red[tid][0], red[tid][1]),
                     fmaxf(red[tid][2], red[tid][3]));
    maxv[tid] = (mm > -8.9e15f) ? mm : 0.f;  // guard fully-masked row
  }
  __syncthreads();

  // ---- pass 2: p generation + weighted accumulation of kcWh ----
  float acc[TR], dpart[TR];
#pragma unroll
  for (int r = 0; r < TR; ++r) { acc[r] = 0.f; dpart[r] = 0.f; }

  for (int jb = 0; jb < N_KC; jb += 256) {
    int cs = min(256, N_KC - jb);
    __syncthreads();
    if (tid < cs) {
      float tv = t_s[jb + tid];
#pragma unroll
      for (int r = 0; r < TR; ++r) {
        int av = adj[(size_t)(i0 + r) * N_KC + jb + tid];
        float x = s_sh[r] + tv;
        float lx = x > 0.f ? x : ALPHA * x;
        float p = (av > 0) ? __expf(lx - maxv[r]) : 0.f;
        buf[r * 256 + tid] = p;
        dpart[r] += p;
      }
    }
    __syncthreads();
    for (int jj = 0; jj < cs; jj += 4) {
      float k0 = g_kcWh[(size_t)(jb + jj + 0) * 256 + tid];
      float k1 = g_kcWh[(size_t)(jb + jj + 1) * 256 + tid];
      float k2 = g_kcWh[(size_t)(jb + jj + 2) * 256 + tid];
      float k3 = g_kcWh[(size_t)(jb + jj + 3) * 256 + tid];
#pragma unroll
      for (int r = 0; r < TR; ++r) {
        float4 p4 = *(const float4*)&buf[r * 256 + jj];
        float a0 = fmaf(p4.x, k0, acc[r]);
        float a1 = fmaf(p4.y, k1, a0);
        float a2 = fmaf(p4.z, k2, a1);
        acc[r] = fmaf(p4.w, k3, a2);
      }
    }
  }

  // ---- denominator reduction ----
  for (int r = 0; r < TR; ++r) {
    float d = dpart[r];
    for (int off = 32; off; off >>= 1) d += __shfl_down(d, off, 64);
    if ((tid & 63) == 0) red[r][tid >> 6] = d;
  }
  __syncthreads();
  if (tid < TR) {
    float dn = red[tid][0] + red[tid][1] + red[tid][2] + red[tid][3];
    denom[tid] = (dn > 0.f) ? dn : 1.f;
  }
  __syncthreads();

  // ---- phase C: ex_Eh rows (reuse buf for exh rows as f32) ----
  for (int r = 0; r < TR; ++r)
    buf[r * 256 + tid] = ldin(exh, (size_t)(i0 + r) * 256 + tid, f32);
  __syncthreads();
  float eacc[TR];
#pragma unroll
  for (int r = 0; r < TR; ++r) eacc[r] = 0.f;
  for (int k = 0; k < 256; k += 4) {
    float e0 = ldin(E, (size_t)(k + 0) * 256 + tid, f32);
    float e1 = ldin(E, (size_t)(k + 1) * 256 + tid, f32);
    float e2 = ldin(E, (size_t)(k + 2) * 256 + tid, f32);
    float e3 = ldin(E, (size_t)(k + 3) * 256 + tid, f32);
#pragma unroll
    for (int r = 0; r < TR; ++r) {
      float4 x4 = *(const float4*)&buf[r * 256 + k];
      float a0 = fmaf(x4.x, e0, eacc[r]);
      float a1 = fmaf(x4.y, e1, a0);
      float a2 = fmaf(x4.z, e2, a1);
      eacc[r] = fmaf(x4.w, e3, a2);
    }
  }
  __syncthreads();

  // ---- phase D: feat = [new_kc, new_kc*ex_Eh]; out = elu(feat @ rd_w^T + b)
  for (int r = 0; r < TR; ++r) {
    float nk = acc[r] / denom[r];
    buf[r * 512 + tid] = nk;
    buf[r * 512 + 256 + tid] = nk * eacc[r];
  }
  __syncthreads();
  float bias = ldin(rd_b, tid, f32);
  float oacc[TR];
#pragma unroll
  for (int r = 0; r < TR; ++r) oacc[r] = bias;
  for (int o = 0; o < 512; o += 4) {
    float w0 = g_rdwT[(o + 0) * 256 + tid];
    float w1 = g_rdwT[(o + 1) * 256 + tid];
    float w2 = g_rdwT[(o + 2) * 256 + tid];
    float w3 = g_rdwT[(o + 3) * 256 + tid];
#pragma unroll
    for (int r = 0; r < TR; ++r) {
      float4 f4 = *(const float4*)&buf[r * 512 + o];
      float a0 = fmaf(f4.x, w0, oacc[r]);
      float a1 = fmaf(f4.y, w1, a0);
      float a2 = fmaf(f4.z, w2, a1);
      oacc[r] = fmaf(f4.w, w3, a2);
    }
  }
  for (int r = 0; r < TR; ++r) {
    float x = oacc[r];
    float res = x > 0.f ? x : (expf(x) - 1.f);
    out[(size_t)(i0 + r) * 256 + tid] = res;  // f32 OUTPUT
  }
}

extern "C" void kernel_launch(void* const* d_in, const int* in_sizes, int n_in,
                              void* d_out, int out_size, void* d_ws,
                              size_t ws_size, hipStream_t stream) {
  const void* exh  = d_in[0];
  const void* kc_h = d_in[1];
  const int*  adj  = (const int*)d_in[2];
  const void* W1   = d_in[3];
  const void* E    = d_in[4];
  const void* a    = d_in[5];
  const void* rd_w = d_in[6];
  const void* rd_b = d_in[7];
  float* out = (float*)d_out;

  prep_kernel<<<513, 256, 0, stream>>>(W1, a, rd_w);
  kc_kernel<<<N_KC, 256, 0, stream>>>(kc_h, W1, a);
  s_kernel<<<N_E / 4, 256, 0, stream>>>(exh, W1);
  main_kernel<<<N_E / TR, 256, 0, stream>>>(exh, adj, E, W1, rd_b, out);
}

// Round 5
// 310.792 us; speedup vs baseline: 2.4674x; 2.4674x over previous
//
#include <hip/hip_runtime.h>

#define N_E 10000
#define N_KC 2000
#define KPAD 2048
#define ALPHA 0.2f

typedef __attribute__((ext_vector_type(8))) short short8;
typedef __attribute__((ext_vector_type(4))) float f32x4;

// ---- static device scratch (fully rewritten every call) ----
__device__ float g_w1a1[256];
__device__ float g_w1a2[256];
__device__ float g_s[N_E];
__device__ float g_t[KPAD];                        // [2000,2048) zeroed
__device__ unsigned short g_exh_bf[N_E * 256];     // bf16 rows of exercise_h
__device__ unsigned short g_kc_bf[N_KC * 256];     // bf16 rows of kc_h
__device__ unsigned short g_W1T_bf[256 * 256];     // [o][k]
__device__ unsigned short g_ET_bf[256 * 256];      // [o][k]
__device__ unsigned short g_rdw_bf[256 * 512];     // [c][f] (orig layout)
__device__ unsigned short g_kcWhT_bf[256 * KPAD];  // [o][j], j>=2000 zero

__device__ __forceinline__ unsigned short f2bf(float f) {
  union { float f; unsigned int u; } v; v.f = f;
  unsigned int r = v.u + 0x7FFFu + ((v.u >> 16) & 1u);
  return (unsigned short)(r >> 16);
}

__device__ __forceinline__ void cvt_store4(float4 v, unsigned short* dst) {
  ushort4 o;
  o.x = f2bf(v.x); o.y = f2bf(v.y); o.z = f2bf(v.z); o.w = f2bf(v.w);
  *reinterpret_cast<ushort4*>(dst) = o;
}

// ---- prep: bf16 conversions/transposes + w1a1/w1a2 + zero pads ----
__global__ __launch_bounds__(256) void prep_kernel(
    const float* __restrict__ exh, const float* __restrict__ kc_h,
    const float* __restrict__ W1, const float* __restrict__ E,
    const float* __restrict__ a, const float* __restrict__ rd_w) {
  int b = blockIdx.x, tid = threadIdx.x;
  if (b < 625) {                 // exh -> bf16 : 640000 float4
    for (int q = 0; q < 4; ++q) {
      int idx = b * 1024 + q * 256 + tid;
      cvt_store4(((const float4*)exh)[idx], g_exh_bf + (size_t)idx * 4);
    }
  } else if (b < 750) {          // kc_h -> bf16 : 128000 float4
    for (int q = 0; q < 4; ++q) {
      int idx = (b - 625) * 1024 + q * 256 + tid;
      cvt_store4(((const float4*)kc_h)[idx], g_kc_bf + (size_t)idx * 4);
    }
  } else if (b < 782) {          // rd_w -> bf16 : 32768 float4
    for (int q = 0; q < 4; ++q) {
      int idx = (b - 750) * 1024 + q * 256 + tid;
      cvt_store4(((const float4*)rd_w)[idx], g_rdw_bf + (size_t)idx * 4);
    }
  } else if (b < 1038) {         // E^T
    int o = b - 782;
    g_ET_bf[o * 256 + tid] = f2bf(E[tid * 256 + o]);
  } else if (b < 1294) {         // W1^T
    int o = b - 1038;
    g_W1T_bf[o * 256 + tid] = f2bf(W1[tid * 256 + o]);
  } else if (b < 1296) {         // w1a1 / w1a2
    const float* av = a + (b - 1294) * 256;
    float acc = 0.f;
    for (int q = 0; q < 64; ++q) {
      float4 wv = *(const float4*)(W1 + (size_t)tid * 256 + q * 4);
      float4 a4 = *(const float4*)(av + q * 4);
      acc += wv.x * a4.x + wv.y * a4.y + wv.z * a4.z + wv.w * a4.w;
    }
    if (b == 1294) g_w1a1[tid] = acc; else g_w1a2[tid] = acc;
  } else {                       // zero pads
    for (int q = tid; q < 256 * 48; q += 256)
      g_kcWhT_bf[(size_t)(q / 48) * KPAD + 2000 + (q % 48)] = 0;
    if (tid < 48) g_t[2000 + tid] = 0.f;
  }
}

// ---- s[i] = exh[i]·w1a1 ; t[j] = kc_h[j]·w1a2 (one wave per row) ----
__global__ __launch_bounds__(256) void st_kernel(
    const float* __restrict__ exh, const float* __restrict__ kc_h) {
  int tid = threadIdx.x, lane = tid & 63, w = tid >> 6;
  int row = blockIdx.x * 4 + w;
  bool is_s = row < N_E;
  const float* src = is_s ? (exh + (size_t)row * 256)
                          : (kc_h + (size_t)(row - N_E) * 256);
  const float* wv = is_s ? g_w1a1 : g_w1a2;
  float4 x = *(const float4*)(src + lane * 4);
  float4 c = *(const float4*)(wv + lane * 4);
  float d = x.x * c.x + x.y * c.y + x.z * c.z + x.w * c.w;
  for (int off = 32; off; off >>= 1) d += __shfl_down(d, off, 64);
  if (lane == 0) { if (is_s) g_s[row] = d; else g_t[row - N_E] = d; }
}

// ---- kcWhT[o][j] = (kc_h @ W1)^T in bf16 via MFMA: 125 blocks x 16 rows ----
__global__ __launch_bounds__(256) void kc_mfma_kernel() {
  int tid = threadIdx.x, lane = tid & 63, w = tid >> 6;
  int r = lane & 15, g = lane >> 4;
  int j0 = blockIdx.x * 16;
  int c0 = w * 64;
  f32x4 acc[4] = {{0.f,0.f,0.f,0.f},{0.f,0.f,0.f,0.f},
                  {0.f,0.f,0.f,0.f},{0.f,0.f,0.f,0.f}};
  for (int kk = 0; kk < 8; ++kk) {
    int k = kk * 32 + g * 8;
    short8 afrag = *(const short8*)(g_kc_bf + (size_t)(j0 + r) * 256 + k);
#pragma unroll
    for (int n = 0; n < 4; ++n) {
      short8 bfrag =
          *(const short8*)(g_W1T_bf + (size_t)(c0 + n * 16 + r) * 256 + k);
      acc[n] = __builtin_amdgcn_mfma_f32_16x16x32_bf16(afrag, bfrag, acc[n],
                                                       0, 0, 0);
    }
  }
#pragma unroll
  for (int n = 0; n < 4; ++n) {
    int col = c0 + n * 16 + r;
    ushort4 o;
    o.x = f2bf(acc[n][0]); o.y = f2bf(acc[n][1]);
    o.z = f2bf(acc[n][2]); o.w = f2bf(acc[n][3]);
    *reinterpret_cast<ushort4*>(g_kcWhT_bf + (size_t)col * KPAD + j0 + g * 4) = o;
  }
}

// ---- main: P-gen + P@kcWh + exh@E + gate + feat@rd_w^T + ELU, all MFMA ----
__global__ __launch_bounds__(256) void main_kernel(
    const int* __restrict__ adj, const float* __restrict__ rd_b,
    float* __restrict__ out) {
  __shared__ float t_s[KPAD];
  __shared__ unsigned short feat_s[16 * 520];  // stride 520: bank-safe
  int tid = threadIdx.x, lane = tid & 63, w = tid >> 6;
  int r = lane & 15, g = lane >> 4;
  int i0 = blockIdx.x * 16;
  int c0w = w * 64;

  for (int q = tid; q < KPAD / 4; q += 256)
    ((float4*)t_s)[q] = ((const float4*)g_t)[q];
  float sv = g_s[i0 + r];
  __syncthreads();

  // ---- attention GEMM: accP = P(16x2000) @ kcWh(2000x256), K-tiled x32 ----
  f32x4 accP[4] = {{0.f,0.f,0.f,0.f},{0.f,0.f,0.f,0.f},
                   {0.f,0.f,0.f,0.f},{0.f,0.f,0.f,0.f}};
  float dsum = 0.f;
  const int* arow = adj + (size_t)(i0 + r) * N_KC;

  for (int kk = 0; kk < 63; ++kk) {
    int c0 = kk * 32 + g * 8;
    short8 afrag = {0, 0, 0, 0, 0, 0, 0, 0};
    if (c0 < N_KC) {  // whole 8-chunk valid (2000 % 8 == 0)
      int4 av0 = *(const int4*)(arow + c0);
      int4 av1 = *(const int4*)(arow + c0 + 4);
      float4 t0 = *(const float4*)(t_s + c0);
      float4 t1 = *(const float4*)(t_s + c0 + 4);
      float tv[8] = {t0.x, t0.y, t0.z, t0.w, t1.x, t1.y, t1.z, t1.w};
      int av[8] = {av0.x, av0.y, av0.z, av0.w, av1.x, av1.y, av1.z, av1.w};
#pragma unroll
      for (int j = 0; j < 8; ++j) {
        float x = sv + tv[j];
        float lx = x > 0.f ? x : ALPHA * x;
        float pv = (av[j] > 0) ? __expf(lx) : 0.f;  // no max-sub: |lx|<~15
        dsum += pv;
        afrag[j] = (short)f2bf(pv);
      }
    }
#pragma unroll
    for (int n = 0; n < 4; ++n) {
      short8 bfrag = *(const short8*)(g_kcWhT_bf +
                                      (size_t)(c0w + n * 16 + r) * KPAD +
                                      kk * 32 + g * 8);
      accP[n] = __builtin_amdgcn_mfma_f32_16x16x32_bf16(afrag, bfrag, accP[n],
                                                        0, 0, 0);
    }
  }

  // denominator: lanes {r, r+16, r+32, r+48} hold partials for row r
  dsum += __shfl_xor(dsum, 16, 64);
  dsum += __shfl_xor(dsum, 32, 64);
  float dn[4];
#pragma unroll
  for (int q = 0; q < 4; ++q)
    dn[q] = 1.f / fmaxf(__shfl(dsum, g * 4 + q, 64), 1e-30f);

  // ---- ex_Eh GEMM: exh(16x256) @ E(256x256) -> same C/D layout as accP ----
  f32x4 accE[4] = {{0.f,0.f,0.f,0.f},{0.f,0.f,0.f,0.f},
                   {0.f,0.f,0.f,0.f},{0.f,0.f,0.f,0.f}};
  for (int kk = 0; kk < 8; ++kk) {
    int k = kk * 32 + g * 8;
    short8 afrag = *(const short8*)(g_exh_bf + (size_t)(i0 + r) * 256 + k);
#pragma unroll
    for (int n = 0; n < 4; ++n) {
      short8 bfrag =
          *(const short8*)(g_ET_bf + (size_t)(c0w + n * 16 + r) * 256 + k);
      accE[n] = __builtin_amdgcn_mfma_f32_16x16x32_bf16(afrag, bfrag, accE[n],
                                                        0, 0, 0);
    }
  }

  // ---- feat = [new_kc | new_kc * ex_Eh] -> LDS (bf16, A-layout source) ----
#pragma unroll
  for (int n = 0; n < 4; ++n) {
    int col = c0w + n * 16 + r;
#pragma unroll
    for (int q = 0; q < 4; ++q) {
      int row = g * 4 + q;
      float nk = accP[n][q] * dn[q];
      feat_s[row * 520 + col] = f2bf(nk);
      feat_s[row * 520 + 256 + col] = f2bf(nk * accE[n][q]);
    }
  }
  __syncthreads();

  // ---- epilogue GEMM: feat(16x512) @ rd_w^T(512x256) + bias, ELU ----
  f32x4 accO[4] = {{0.f,0.f,0.f,0.f},{0.f,0.f,0.f,0.f},
                   {0.f,0.f,0.f,0.f},{0.f,0.f,0.f,0.f}};
  for (int kk = 0; kk < 16; ++kk) {
    int k = kk * 32 + g * 8;
    short8 afrag = *(const short8*)(feat_s + r * 520 + k);
#pragma unroll
    for (int n = 0; n < 4; ++n) {
      short8 bfrag =
          *(const short8*)(g_rdw_bf + (size_t)(c0w + n * 16 + r) * 512 + k);
      accO[n] = __builtin_amdgcn_mfma_f32_16x16x32_bf16(afrag, bfrag, accO[n],
                                                        0, 0, 0);
    }
  }
#pragma unroll
  for (int n = 0; n < 4; ++n) {
    int col = c0w + n * 16 + r;
    float bias = rd_b[col];
#pragma unroll
    for (int q = 0; q < 4; ++q) {
      int row = g * 4 + q;
      float x = accO[n][q] + bias;
      float res = x > 0.f ? x : (__expf(x) - 1.f);
      out[(size_t)(i0 + row) * 256 + col] = res;
    }
  }
}

extern "C" void kernel_launch(void* const* d_in, const int* in_sizes, int n_in,
                              void* d_out, int out_size, void* d_ws,
                              size_t ws_size, hipStream_t stream) {
  const float* exh  = (const float*)d_in[0];
  const float* kc_h = (const float*)d_in[1];
  const int*   adj  = (const int*)d_in[2];
  const float* W1   = (const float*)d_in[3];
  const float* E    = (const float*)d_in[4];
  const float* a    = (const float*)d_in[5];
  const float* rd_w = (const float*)d_in[6];
  const float* rd_b = (const float*)d_in[7];
  float* out = (float*)d_out;

  prep_kernel<<<1297, 256, 0, stream>>>(exh, kc_h, W1, E, a, rd_w);
  st_kernel<<<(N_E + N_KC) / 4, 256, 0, stream>>>(exh, kc_h);
  kc_mfma_kernel<<<N_KC / 16, 256, 0, stream>>>();
  main_kernel<<<N_E / 16, 256, 0, stream>>>(adj, rd_b, out);
}

// Round 6
// 279.949 us; speedup vs baseline: 2.7392x; 1.1102x over previous
//
#include <hip/hip_runtime.h>

#define N_E 10000
#define N_KC 2000
#define KPAD 2048
#define ALPHA 0.2f

typedef __attribute__((ext_vector_type(8))) short short8;
typedef __attribute__((ext_vector_type(4))) float f32x4;

// ---- static device scratch (fully rewritten every call) ----
__device__ float g_w1a1[256];
__device__ float g_w1a2[256];
__device__ float g_s[N_E];
__device__ float g_t[KPAD];                        // [2000,2048) zeroed
__device__ __align__(16) unsigned short g_exh_bf[N_E * 256];
__device__ __align__(16) unsigned short g_kc_bf[N_KC * 256];
__device__ __align__(16) unsigned short g_W1T_bf[256 * 256];   // [o][k]
__device__ __align__(16) unsigned short g_ET_bf[256 * 256];    // [o][k]
__device__ __align__(16) unsigned short g_rdw_bf[256 * 512];   // [c][f]
__device__ __align__(16) unsigned short g_kcWhT_bf[256 * KPAD];// [o][j]

__device__ __forceinline__ unsigned short f2bf(float f) {
  union { float f; unsigned int u; } v; v.f = f;
  unsigned int r = v.u + 0x7FFFu + ((v.u >> 16) & 1u);
  return (unsigned short)(r >> 16);
}

__device__ __forceinline__ void cvt_store4(float4 v, unsigned short* dst) {
  ushort4 o;
  o.x = f2bf(v.x); o.y = f2bf(v.y); o.z = f2bf(v.z); o.w = f2bf(v.w);
  *reinterpret_cast<ushort4*>(dst) = o;
}

// ---- prep: bf16 conversions/transposes + w1a1/w1a2 + zero pads ----
__global__ __launch_bounds__(256) void prep_kernel(
    const float* __restrict__ exh, const float* __restrict__ kc_h,
    const float* __restrict__ W1, const float* __restrict__ E,
    const float* __restrict__ a, const float* __restrict__ rd_w) {
  int b = blockIdx.x, tid = threadIdx.x;
  if (b < 625) {
    for (int q = 0; q < 4; ++q) {
      int idx = b * 1024 + q * 256 + tid;
      cvt_store4(((const float4*)exh)[idx], g_exh_bf + (size_t)idx * 4);
    }
  } else if (b < 750) {
    for (int q = 0; q < 4; ++q) {
      int idx = (b - 625) * 1024 + q * 256 + tid;
      cvt_store4(((const float4*)kc_h)[idx], g_kc_bf + (size_t)idx * 4);
    }
  } else if (b < 782) {
    for (int q = 0; q < 4; ++q) {
      int idx = (b - 750) * 1024 + q * 256 + tid;
      cvt_store4(((const float4*)rd_w)[idx], g_rdw_bf + (size_t)idx * 4);
    }
  } else if (b < 1038) {
    int o = b - 782;
    g_ET_bf[o * 256 + tid] = f2bf(E[tid * 256 + o]);
  } else if (b < 1294) {
    int o = b - 1038;
    g_W1T_bf[o * 256 + tid] = f2bf(W1[tid * 256 + o]);
  } else if (b < 1296) {
    const float* av = a + (b - 1294) * 256;
    float acc = 0.f;
    for (int q = 0; q < 64; ++q) {
      float4 wv = *(const float4*)(W1 + (size_t)tid * 256 + q * 4);
      float4 a4 = *(const float4*)(av + q * 4);
      acc += wv.x * a4.x + wv.y * a4.y + wv.z * a4.z + wv.w * a4.w;
    }
    if (b == 1294) g_w1a1[tid] = acc; else g_w1a2[tid] = acc;
  } else {
    for (int q = tid; q < 256 * 48; q += 256)
      g_kcWhT_bf[(size_t)(q / 48) * KPAD + 2000 + (q % 48)] = 0;
    if (tid < 48) g_t[2000 + tid] = 0.f;
  }
}

// ---- s[i] = exh[i]·w1a1 ; t[j] = kc_h[j]·w1a2 ----
__global__ __launch_bounds__(256) void st_kernel(
    const float* __restrict__ exh, const float* __restrict__ kc_h) {
  int tid = threadIdx.x, lane = tid & 63, w = tid >> 6;
  int row = blockIdx.x * 4 + w;
  bool is_s = row < N_E;
  const float* src = is_s ? (exh + (size_t)row * 256)
                          : (kc_h + (size_t)(row - N_E) * 256);
  const float* wv = is_s ? g_w1a1 : g_w1a2;
  float4 x = *(const float4*)(src + lane * 4);
  float4 c = *(const float4*)(wv + lane * 4);
  float d = x.x * c.x + x.y * c.y + x.z * c.z + x.w * c.w;
  for (int off = 32; off; off >>= 1) d += __shfl_down(d, off, 64);
  if (lane == 0) { if (is_s) g_s[row] = d; else g_t[row - N_E] = d; }
}

// ---- kcWhT[o][j] = (kc_h @ W1)^T via MFMA ----
__global__ __launch_bounds__(256) void kc_mfma_kernel() {
  int tid = threadIdx.x, lane = tid & 63, w = tid >> 6;
  int r = lane & 15, g = lane >> 4;
  int j0 = blockIdx.x * 16;
  int c0 = w * 64;
  f32x4 acc[4] = {{0.f,0.f,0.f,0.f},{0.f,0.f,0.f,0.f},
                  {0.f,0.f,0.f,0.f},{0.f,0.f,0.f,0.f}};
  for (int kk = 0; kk < 8; ++kk) {
    int k = kk * 32 + g * 8;
    short8 afrag = *(const short8*)(g_kc_bf + (size_t)(j0 + r) * 256 + k);
#pragma unroll
    for (int n = 0; n < 4; ++n) {
      short8 bfrag =
          *(const short8*)(g_W1T_bf + (size_t)(c0 + n * 16 + r) * 256 + k);
      acc[n] = __builtin_amdgcn_mfma_f32_16x16x32_bf16(afrag, bfrag, acc[n],
                                                       0, 0, 0);
    }
  }
#pragma unroll
  for (int n = 0; n < 4; ++n) {
    int col = c0 + n * 16 + r;
    ushort4 o;
    o.x = f2bf(acc[n][0]); o.y = f2bf(acc[n][1]);
    o.z = f2bf(acc[n][2]); o.w = f2bf(acc[n][3]);
    *reinterpret_cast<ushort4*>(g_kcWhT_bf + (size_t)col * KPAD + j0 + g * 4) = o;
  }
}

// ---- main: cooperative chunked P-gen via LDS + 3 MFMA GEMMs ----
#define PST 280   // p_s row stride (shorts): 16B-aligned, ~2-way banks
#define FST 536   // feat row stride (shorts)
__global__ __launch_bounds__(512) void main_kernel(
    const int* __restrict__ adj, const float* __restrict__ rd_b,
    float* __restrict__ out) {
  __shared__ float t_s[KPAD];
  __shared__ __align__(16) unsigned short p_s[2][16 * PST];
  __shared__ __align__(16) unsigned short feat_s[16 * FST];
  __shared__ float ds_part[8][16];
  __shared__ float dtot[16];

  int tid = threadIdx.x;
  int w = tid >> 6, lane = tid & 63;
  int r = lane & 15, g = lane >> 4;
  int i0 = blockIdx.x * 16;
  int c0e = w * 32;

  for (int q = tid; q < KPAD / 4; q += 512)
    ((float4*)t_s)[q] = ((const float4*)g_t)[q];
  float sv = g_s[i0 + r];
  const int* arow = adj + (size_t)(i0 + r) * N_KC;
  __syncthreads();

  f32x4 accP[2] = {{0.f,0.f,0.f,0.f},{0.f,0.f,0.f,0.f}};
  float dsum = 0.f;

  // -- generate P for chunk c (wave w handles kk = c*8+w) into p_s[c&1] --
  auto gen = [&](int c) {
    int kk = c * 8 + w;
    unsigned short* dst = &p_s[c & 1][r * PST + w * 32 + g * 8];
    int c0 = kk * 32 + g * 8;
    int4 pk = {0, 0, 0, 0};
    if (kk < 63 && c0 < N_KC) {
      int4 a0 = *(const int4*)(arow + c0);
      int4 a1 = *(const int4*)(arow + c0 + 4);
      float4 t0 = *(const float4*)(t_s + c0);
      float4 t1 = *(const float4*)(t_s + c0 + 4);
      float tv[8] = {t0.x, t0.y, t0.z, t0.w, t1.x, t1.y, t1.z, t1.w};
      int av[8] = {a0.x, a0.y, a0.z, a0.w, a1.x, a1.y, a1.z, a1.w};
      unsigned int ub[8];
#pragma unroll
      for (int j = 0; j < 8; ++j) {
        float x = sv + tv[j];
        float lx = fmaxf(x, ALPHA * x);
        float pv = (av[j] > 0) ? __expf(lx) : 0.f;
        dsum += pv;
        ub[j] = __float_as_uint(pv) + 0x8000u;  // round-half-up to bf16
      }
      pk.x = (int)((ub[0] >> 16) | (ub[1] & 0xFFFF0000u));
      pk.y = (int)((ub[2] >> 16) | (ub[3] & 0xFFFF0000u));
      pk.z = (int)((ub[4] >> 16) | (ub[5] & 0xFFFF0000u));
      pk.w = (int)((ub[6] >> 16) | (ub[7] & 0xFFFF0000u));
    }
    *(int4*)dst = pk;
  };

  auto mfma_chunk = [&](int c) {
#pragma unroll
    for (int u = 0; u < 8; ++u) {
      int kk = c * 8 + u;
      short8 af = *(const short8*)&p_s[c & 1][r * PST + u * 32 + g * 8];
#pragma unroll
      for (int n = 0; n < 2; ++n) {
        short8 bf = *(const short8*)(g_kcWhT_bf +
                                     (size_t)(c0e + n * 16 + r) * KPAD +
                                     kk * 32 + g * 8);
        accP[n] = __builtin_amdgcn_mfma_f32_16x16x32_bf16(af, bf, accP[n],
                                                          0, 0, 0);
      }
    }
  };

  gen(0);
  __syncthreads();
  for (int c = 1; c < 8; ++c) {
    gen(c);            // writes p_s[c&1]; overlaps with mfma of previous chunk
    mfma_chunk(c - 1); // reads p_s[(c-1)&1]
    __syncthreads();
  }
  mfma_chunk(7);

  // -- denominator partials --
  dsum += __shfl_xor(dsum, 16, 64);
  dsum += __shfl_xor(dsum, 32, 64);
  if (lane < 16) ds_part[w][lane] = dsum;

  // -- ex_Eh GEMM (same C/D layout as accP) --
  f32x4 accE[2] = {{0.f,0.f,0.f,0.f},{0.f,0.f,0.f,0.f}};
#pragma unroll
  for (int kk = 0; kk < 8; ++kk) {
    int k = kk * 32 + g * 8;
    short8 af = *(const short8*)(g_exh_bf + (size_t)(i0 + r) * 256 + k);
#pragma unroll
    for (int n = 0; n < 2; ++n) {
      short8 bf =
          *(const short8*)(g_ET_bf + (size_t)(c0e + n * 16 + r) * 256 + k);
      accE[n] = __builtin_amdgcn_mfma_f32_16x16x32_bf16(af, bf, accE[n],
                                                        0, 0, 0);
    }
  }
  __syncthreads();
  if (tid < 16) {
    float s = 0.f;
#pragma unroll
    for (int ww = 0; ww < 8; ++ww) s += ds_part[ww][tid];
    dtot[tid] = 1.f / fmaxf(s, 1e-30f);
  }
  __syncthreads();

  // -- feat = [new_kc | new_kc * ex_Eh] (register-local gating) --
#pragma unroll
  for (int n = 0; n < 2; ++n) {
    int col = c0e + n * 16 + r;
#pragma unroll
    for (int q = 0; q < 4; ++q) {
      int row = g * 4 + q;
      float nk = accP[n][q] * dtot[row];
      feat_s[row * FST + col] = f2bf(nk);
      feat_s[row * FST + 256 + col] = f2bf(nk * accE[n][q]);
    }
  }
  __syncthreads();

  // -- epilogue GEMM: feat(16x512) @ rd_w^T + bias, ELU --
  f32x4 accO[2] = {{0.f,0.f,0.f,0.f},{0.f,0.f,0.f,0.f}};
#pragma unroll
  for (int kk = 0; kk < 16; ++kk) {
    int k = kk * 32 + g * 8;
    short8 af = *(const short8*)&feat_s[r * FST + k];
#pragma unroll
    for (int n = 0; n < 2; ++n) {
      short8 bf =
          *(const short8*)(g_rdw_bf + (size_t)(c0e + n * 16 + r) * 512 + k);
      accO[n] = __builtin_amdgcn_mfma_f32_16x16x32_bf16(af, bf, accO[n],
                                                        0, 0, 0);
    }
  }
#pragma unroll
  for (int n = 0; n < 2; ++n) {
    int col = c0e + n * 16 + r;
    float bias = rd_b[col];
#pragma unroll
    for (int q = 0; q < 4; ++q) {
      int row = g * 4 + q;
      float x = accO[n][q] + bias;
      float res = x > 0.f ? x : (__expf(x) - 1.f);
      out[(size_t)(i0 + row) * 256 + col] = res;
    }
  }
}

extern "C" void kernel_launch(void* const* d_in, const int* in_sizes, int n_in,
                              void* d_out, int out_size, void* d_ws,
                              size_t ws_size, hipStream_t stream) {
  const float* exh  = (const float*)d_in[0];
  const float* kc_h = (const float*)d_in[1];
  const int*   adj  = (const int*)d_in[2];
  const float* W1   = (const float*)d_in[3];
  const float* E    = (const float*)d_in[4];
  const float* a    = (const float*)d_in[5];
  const float* rd_w = (const float*)d_in[6];
  const float* rd_b = (const float*)d_in[7];
  float* out = (float*)d_out;

  prep_kernel<<<1297, 256, 0, stream>>>(exh, kc_h, W1, E, a, rd_w);
  st_kernel<<<(N_E + N_KC) / 4, 256, 0, stream>>>(exh, kc_h);
  kc_mfma_kernel<<<N_KC / 16, 256, 0, stream>>>();
  main_kernel<<<N_E / 16, 512, 0, stream>>>(adj, rd_b, out);
}

// Round 7
// 199.409 us; speedup vs baseline: 3.8456x; 1.4039x over previous
//
#include <hip/hip_runtime.h>

#define N_E 10000
#define N_KC 2000
#define KPAD 2048
#define ALPHA 0.2f

typedef __attribute__((ext_vector_type(8))) short short8;
typedef __attribute__((ext_vector_type(4))) float f32x4;

// ---- static device scratch (fully rewritten every call) ----
__device__ float g_w1a1[256];
__device__ float g_w1a2[256];
__device__ float g_s[N_E];
__device__ float g_t[KPAD];
__device__ __align__(16) unsigned short g_kc_bf[N_KC * 256];      // row-major
// fragment-packed operands: [(tile)*512 + lane*8 + j] shorts
__device__ __align__(16) unsigned short g_exh_pk[625 * 8 * 512];  // A: exh
__device__ __align__(16) unsigned short g_W1T_pk[16 * 8 * 512];   // B: W1^T
__device__ __align__(16) unsigned short g_ET_pk[16 * 8 * 512];    // B: E^T
__device__ __align__(16) unsigned short g_rdw_pk[16 * 16 * 512];  // B: rd_w
__device__ __align__(16) unsigned short g_kcWh_pk[16 * 64 * 512]; // B: kcWh^T

__device__ __forceinline__ unsigned short f2bf(float f) {
  union { float f; unsigned int u; } v; v.f = f;
  unsigned int r = v.u + 0x7FFFu + ((v.u >> 16) & 1u);
  return (unsigned short)(r >> 16);
}

__device__ __forceinline__ void cvt_store4(float4 v, unsigned short* dst) {
  ushort4 o;
  o.x = f2bf(v.x); o.y = f2bf(v.y); o.z = f2bf(v.z); o.w = f2bf(v.w);
  *reinterpret_cast<ushort4*>(dst) = o;
}

// ---- prep: pack operands into fragment-major bf16 + small vectors ----
__global__ __launch_bounds__(256) void prep_kernel(
    const float* __restrict__ exh, const float* __restrict__ kc_h,
    const float* __restrict__ W1, const float* __restrict__ E,
    const float* __restrict__ a, const float* __restrict__ rd_w) {
  int b = blockIdx.x, tid = threadIdx.x;
  if (b < 625) {  // exh -> packed A tiles (block = 16-row tile)
#pragma unroll
    for (int s2 = 0; s2 < 2; ++s2) {
      int sId = tid + s2 * 256;          // 512 slots: kt(8) x lane(64)
      int kt = sId >> 6, lane = sId & 63;
      int g = lane >> 4, r = lane & 15;
      const float* src = exh + (size_t)(b * 16 + r) * 256 + kt * 32 + g * 8;
      unsigned short* dst = g_exh_pk + ((size_t)b * 8 + kt) * 512 + lane * 8;
      cvt_store4(*(const float4*)src, dst);
      cvt_store4(*(const float4*)(src + 4), dst + 4);
    }
  } else if (b < 750) {  // kc_h -> bf16 row-major (A of kc_mfma)
    for (int q = 0; q < 4; ++q) {
      int idx = (b - 625) * 1024 + q * 256 + tid;
      cvt_store4(((const float4*)kc_h)[idx], g_kc_bf + (size_t)idx * 4);
    }
  } else if (b < 782) {  // rd_w -> packed B (ct 16 x kt 16)
#pragma unroll
    for (int s2 = 0; s2 < 2; ++s2) {
      int sId = (b - 750) * 512 + tid + s2 * 256;  // ct*1024 + kt*64 + lane
      int ct = sId >> 10, rem = sId & 1023;
      int kt = rem >> 6, lane = rem & 63;
      int g = lane >> 4, r = lane & 15;
      const float* src = rd_w + (size_t)(ct * 16 + r) * 512 + kt * 32 + g * 8;
      unsigned short* dst = g_rdw_pk + (size_t)sId * 8;
      cvt_store4(*(const float4*)src, dst);
      cvt_store4(*(const float4*)(src + 4), dst + 4);
    }
  } else if (b < 798) {  // W1^T -> packed B (ct 16 x kt 8)
#pragma unroll
    for (int s2 = 0; s2 < 2; ++s2) {
      int sId = (b - 782) * 512 + tid + s2 * 256;
      int ct = sId >> 9, rem = sId & 511;
      int kt = rem >> 6, lane = rem & 63;
      int g = lane >> 4, r = lane & 15;
      int col = ct * 16 + r, k = kt * 32 + g * 8;
      unsigned short* dst = g_W1T_pk + (size_t)sId * 8;
      ushort4 o0, o1;
      o0.x = f2bf(W1[(k + 0) * 256 + col]); o0.y = f2bf(W1[(k + 1) * 256 + col]);
      o0.z = f2bf(W1[(k + 2) * 256 + col]); o0.w = f2bf(W1[(k + 3) * 256 + col]);
      o1.x = f2bf(W1[(k + 4) * 256 + col]); o1.y = f2bf(W1[(k + 5) * 256 + col]);
      o1.z = f2bf(W1[(k + 6) * 256 + col]); o1.w = f2bf(W1[(k + 7) * 256 + col]);
      *(ushort4*)dst = o0; *(ushort4*)(dst + 4) = o1;
    }
  } else if (b < 814) {  // E^T -> packed B
#pragma unroll
    for (int s2 = 0; s2 < 2; ++s2) {
      int sId = (b - 798) * 512 + tid + s2 * 256;
      int ct = sId >> 9, rem = sId & 511;
      int kt = rem >> 6, lane = rem & 63;
      int g = lane >> 4, r = lane & 15;
      int col = ct * 16 + r, k = kt * 32 + g * 8;
      unsigned short* dst = g_ET_pk + (size_t)sId * 8;
      ushort4 o0, o1;
      o0.x = f2bf(E[(k + 0) * 256 + col]); o0.y = f2bf(E[(k + 1) * 256 + col]);
      o0.z = f2bf(E[(k + 2) * 256 + col]); o0.w = f2bf(E[(k + 3) * 256 + col]);
      o1.x = f2bf(E[(k + 4) * 256 + col]); o1.y = f2bf(E[(k + 5) * 256 + col]);
      o1.z = f2bf(E[(k + 6) * 256 + col]); o1.w = f2bf(E[(k + 7) * 256 + col]);
      *(ushort4*)dst = o0; *(ushort4*)(dst + 4) = o1;
    }
  } else if (b < 816) {  // w1a1 / w1a2
    const float* av = a + (b - 814) * 256;
    float acc = 0.f;
    for (int q = 0; q < 64; ++q) {
      float4 wv = *(const float4*)(W1 + (size_t)tid * 256 + q * 4);
      float4 a4 = *(const float4*)(av + q * 4);
      acc += wv.x * a4.x + wv.y * a4.y + wv.z * a4.z + wv.w * a4.w;
    }
    if (b == 814) g_w1a1[tid] = acc; else g_w1a2[tid] = acc;
  } else {  // zero pads: g_t tail + kcWh_pk kTiles 62,63
    for (int idx = tid; idx < 16 * 2 * 512; idx += 256) {
      int ct = idx >> 10, rem = idx & 1023;
      int kt = 62 + (rem >> 9), off = rem & 511;
      g_kcWh_pk[((size_t)ct * 64 + kt) * 512 + off] = 0;
    }
    if (tid < 48) g_t[2000 + tid] = 0.f;
  }
}

// ---- s[i] = exh[i]·w1a1 ; t[j] = kc_h[j]·w1a2 ----
__global__ __launch_bounds__(256) void st_kernel(
    const float* __restrict__ exh, const float* __restrict__ kc_h) {
  int tid = threadIdx.x, lane = tid & 63, w = tid >> 6;
  int row = blockIdx.x * 4 + w;
  bool is_s = row < N_E;
  const float* src = is_s ? (exh + (size_t)row * 256)
                          : (kc_h + (size_t)(row - N_E) * 256);
  const float* wv = is_s ? g_w1a1 : g_w1a2;
  float4 x = *(const float4*)(src + lane * 4);
  float4 c = *(const float4*)(wv + lane * 4);
  float d = x.x * c.x + x.y * c.y + x.z * c.z + x.w * c.w;
  for (int off = 32; off; off >>= 1) d += __shfl_down(d, off, 64);
  if (lane == 0) { if (is_s) g_s[row] = d; else g_t[row - N_E] = d; }
}

// ---- kcWh^T via MFMA, output written fragment-packed ----
__global__ __launch_bounds__(256) void kc_mfma_kernel() {
  int tid = threadIdx.x, lane = tid & 63, w = tid >> 6;
  int r = lane & 15, g = lane >> 4;
  int j0 = blockIdx.x * 16;
  f32x4 acc[4] = {{0.f,0.f,0.f,0.f},{0.f,0.f,0.f,0.f},
                  {0.f,0.f,0.f,0.f},{0.f,0.f,0.f,0.f}};
  for (int kk = 0; kk < 8; ++kk) {
    int k = kk * 32 + g * 8;
    short8 afrag = *(const short8*)(g_kc_bf + (size_t)(j0 + r) * 256 + k);
#pragma unroll
    for (int n = 0; n < 4; ++n) {
      short8 bfrag =
          *(const short8*)(g_W1T_pk + ((size_t)(w * 4 + n) * 8 + kk) * 512 +
                           lane * 8);
      acc[n] = __builtin_amdgcn_mfma_f32_16x16x32_bf16(afrag, bfrag, acc[n],
                                                       0, 0, 0);
    }
  }
  // packed store: element (col o, row j): ct=o>>4, kt=j>>5,
  // lane'=((j>>3)&3)*16+(o&15), sub=j&7
  int j = j0 + g * 4;
  int kt = j >> 5, lsub = ((j >> 3) & 3) * 16 + r, sub = (g & 1) * 4;
#pragma unroll
  for (int n = 0; n < 4; ++n) {
    int ct = w * 4 + n;
    ushort4 o;
    o.x = f2bf(acc[n][0]); o.y = f2bf(acc[n][1]);
    o.z = f2bf(acc[n][2]); o.w = f2bf(acc[n][3]);
    *reinterpret_cast<ushort4*>(
        g_kcWh_pk + ((size_t)ct * 64 + kt) * 512 + lsub * 8 + sub) = o;
  }
}

// ---- main: cooperative chunked P-gen via LDS + 3 MFMA GEMMs ----
#define PST 280
#define FST 536
__global__ __launch_bounds__(512) void main_kernel(
    const int* __restrict__ adj, const float* __restrict__ rd_b,
    float* __restrict__ out) {
  __shared__ float t_s[KPAD];
  __shared__ __align__(16) unsigned short p_s[2][16 * PST];
  __shared__ __align__(16) unsigned short feat_s[16 * FST];
  __shared__ float ds_part[8][16];
  __shared__ float dtot[16];

  int tid = threadIdx.x;
  int w = tid >> 6, lane = tid & 63;
  int r = lane & 15, g = lane >> 4;
  int i0 = blockIdx.x * 16;
  int c0e = w * 32;

  for (int q = tid; q < KPAD / 4; q += 512)
    ((float4*)t_s)[q] = ((const float4*)g_t)[q];
  float sv = g_s[i0 + r];
  const int* arow = adj + (size_t)(i0 + r) * N_KC;
  __syncthreads();

  f32x4 accP[2] = {{0.f,0.f,0.f,0.f},{0.f,0.f,0.f,0.f}};
  float dsum = 0.f;

  auto gen = [&](int c) {
    int kk = c * 8 + w;
    unsigned short* dst = &p_s[c & 1][r * PST + w * 32 + g * 8];
    int c0 = kk * 32 + g * 8;
    int4 pk = {0, 0, 0, 0};
    if (kk < 63 && c0 < N_KC) {
      int4 a0 = *(const int4*)(arow + c0);
      int4 a1 = *(const int4*)(arow + c0 + 4);
      float4 t0 = *(const float4*)(t_s + c0);
      float4 t1 = *(const float4*)(t_s + c0 + 4);
      float tv[8] = {t0.x, t0.y, t0.z, t0.w, t1.x, t1.y, t1.z, t1.w};
      int av[8] = {a0.x, a0.y, a0.z, a0.w, a1.x, a1.y, a1.z, a1.w};
      unsigned int ub[8];
#pragma unroll
      for (int j = 0; j < 8; ++j) {
        float x = sv + tv[j];
        float lx = fmaxf(x, ALPHA * x);
        float pv = (av[j] > 0) ? __expf(lx) : 0.f;
        dsum += pv;
        ub[j] = __float_as_uint(pv) + 0x8000u;
      }
      pk.x = (int)((ub[0] >> 16) | (ub[1] & 0xFFFF0000u));
      pk.y = (int)((ub[2] >> 16) | (ub[3] & 0xFFFF0000u));
      pk.z = (int)((ub[4] >> 16) | (ub[5] & 0xFFFF0000u));
      pk.w = (int)((ub[6] >> 16) | (ub[7] & 0xFFFF0000u));
    }
    *(int4*)dst = pk;
  };

  auto mfma_chunk = [&](int c) {
#pragma unroll
    for (int u = 0; u < 8; ++u) {
      int kk = c * 8 + u;
      short8 af = *(const short8*)&p_s[c & 1][r * PST + u * 32 + g * 8];
#pragma unroll
      for (int n = 0; n < 2; ++n) {
        short8 bf = *(const short8*)(g_kcWh_pk +
                                     ((size_t)(w * 2 + n) * 64 + kk) * 512 +
                                     lane * 8);
        accP[n] = __builtin_amdgcn_mfma_f32_16x16x32_bf16(af, bf, accP[n],
                                                          0, 0, 0);
      }
    }
  };

  gen(0);
  __syncthreads();
  for (int c = 1; c < 8; ++c) {
    gen(c);
    mfma_chunk(c - 1);
    __syncthreads();
  }
  mfma_chunk(7);

  dsum += __shfl_xor(dsum, 16, 64);
  dsum += __shfl_xor(dsum, 32, 64);
  if (lane < 16) ds_part[w][lane] = dsum;

  // -- ex_Eh GEMM (packed A and B) --
  f32x4 accE[2] = {{0.f,0.f,0.f,0.f},{0.f,0.f,0.f,0.f}};
#pragma unroll
  for (int kk = 0; kk < 8; ++kk) {
    short8 af = *(const short8*)(g_exh_pk +
                                 ((size_t)blockIdx.x * 8 + kk) * 512 + lane * 8);
#pragma unroll
    for (int n = 0; n < 2; ++n) {
      short8 bf = *(const short8*)(g_ET_pk +
                                   ((size_t)(w * 2 + n) * 8 + kk) * 512 +
                                   lane * 8);
      accE[n] = __builtin_amdgcn_mfma_f32_16x16x32_bf16(af, bf, accE[n],
                                                        0, 0, 0);
    }
  }
  __syncthreads();
  if (tid < 16) {
    float s = 0.f;
#pragma unroll
    for (int ww = 0; ww < 8; ++ww) s += ds_part[ww][tid];
    dtot[tid] = 1.f / fmaxf(s, 1e-30f);
  }
  __syncthreads();

  // -- feat = [new_kc | new_kc * ex_Eh] --
#pragma unroll
  for (int n = 0; n < 2; ++n) {
    int col = c0e + n * 16 + r;
#pragma unroll
    for (int q = 0; q < 4; ++q) {
      int row = g * 4 + q;
      float nk = accP[n][q] * dtot[row];
      feat_s[row * FST + col] = f2bf(nk);
      feat_s[row * FST + 256 + col] = f2bf(nk * accE[n][q]);
    }
  }
  __syncthreads();

  // -- epilogue GEMM: feat(16x512) @ rd_w^T + bias, ELU --
  f32x4 accO[2] = {{0.f,0.f,0.f,0.f},{0.f,0.f,0.f,0.f}};
#pragma unroll
  for (int kk = 0; kk < 16; ++kk) {
    int k = kk * 32 + g * 8;
    short8 af = *(const short8*)&feat_s[r * FST + k];
#pragma unroll
    for (int n = 0; n < 2; ++n) {
      short8 bf = *(const short8*)(g_rdw_pk +
                                   ((size_t)(w * 2 + n) * 16 + kk) * 512 +
                                   lane * 8);
      accO[n] = __builtin_amdgcn_mfma_f32_16x16x32_bf16(af, bf, accO[n],
                                                        0, 0, 0);
    }
  }
#pragma unroll
  for (int n = 0; n < 2; ++n) {
    int col = c0e + n * 16 + r;
    float bias = rd_b[col];
#pragma unroll
    for (int q = 0; q < 4; ++q) {
      int row = g * 4 + q;
      float x = accO[n][q] + bias;
      float res = x > 0.f ? x : (__expf(x) - 1.f);
      out[(size_t)(i0 + row) * 256 + col] = res;
    }
  }
}

extern "C" void kernel_launch(void* const* d_in, const int* in_sizes, int n_in,
                              void* d_out, int out_size, void* d_ws,
                              size_t ws_size, hipStream_t stream) {
  const float* exh  = (const float*)d_in[0];
  const float* kc_h = (const float*)d_in[1];
  const int*   adj  = (const int*)d_in[2];
  const float* W1   = (const float*)d_in[3];
  const float* E    = (const float*)d_in[4];
  const float* a    = (const float*)d_in[5];
  const float* rd_w = (const float*)d_in[6];
  const float* rd_b = (const float*)d_in[7];
  float* out = (float*)d_out;

  prep_kernel<<<817, 256, 0, stream>>>(exh, kc_h, W1, E, a, rd_w);
  st_kernel<<<(N_E + N_KC) / 4, 256, 0, stream>>>(exh, kc_h);
  kc_mfma_kernel<<<N_KC / 16, 256, 0, stream>>>();
  main_kernel<<<N_E / 16, 512, 0, stream>>>(adj, rd_b, out);
}